// Round 5
// baseline (526.215 us; speedup 1.0000x reference)
//
#include <hip/hip_runtime.h>

#define ECE_N_BINS 15

typedef float f32x4 __attribute__((ext_vector_type(4)));

static __device__ __forceinline__ unsigned umax2(unsigned a, unsigned b) {
    return a > b ? a : b;
}

// Fused single kernel. ws layout (memset to 0 by kernel_launch each call):
//   ws[0..14]  = sum_conf per bin
//   ws[15..29] = sum_acc  per bin
//   ws[30]     = block-completion counter (as unsigned)
//
// Main loop: one 64-lane wave owns 16 consecutive rows (8 KB) per iteration;
// lanes 0-31 -> even rows, 32-63 -> odd rows; each lane issues 8 independent
// nontemporal float4 loads. Max+argmax fused into one u32 key per row:
//   key = (float_bits & ~127) | (127 - col)
// (positive floats are bit-order-monotonic; low 7 bits break ties toward the
// first occurrence, matching jnp.argmax). Butterfly = 5 shfl + 5 umax.
// All waves run EXACTLY nChunks/nWaves iterations (no 16th-iteration skew);
// leftover rows are handled by a fine-grained 2-row/wave tail loop.
__global__ __launch_bounds__(256) void ece_fused(const float* __restrict__ sm,
                                                 const int* __restrict__ labels,
                                                 float* __restrict__ ws,
                                                 float* __restrict__ out,
                                                 int N) {
    __shared__ float s_h[4][2][ECE_N_BINS];   // per-wave histograms
    __shared__ int   s_last;

    const int t    = threadIdx.x;
    const int wv   = t >> 6;
    const int lane = t & 63;
    const int half = lane >> 5;          // row parity
    const int s    = lane & 31;          // column group: cols 4s..4s+3
    if (lane < 2 * ECE_N_BINS) ((float*)&s_h[wv][0][0])[lane] = 0.0f;
    __syncthreads();

    const long long waveId = (long long)blockIdx.x * 4 + wv;
    const long long nWaves = (long long)gridDim.x * 4;
    const long long nChunks = (long long)N >> 4;        // 16 rows per chunk
    const long long iters   = nChunks / nWaves;         // uniform per wave

    const float* p = sm + (waveId << 11) + (half << 7) + (s << 2);
    const long long pStride = nWaves << 11;             // floats per stride
    const unsigned base7 = (unsigned)(127 - 4 * s);     // 127 - col base

    for (long long i = 0; i < iters; ++i, p += pStride) {
        const long long c = waveId + i * nWaves;

        // early label prefetch: latency hides under key-build + butterfly
        int lab[8];
        if (s == 0) {
            const long long row0 = (c << 4) + half;
            #pragma unroll
            for (int k = 0; k < 8; ++k) lab[k] = labels[row0 + 2 * k];
        }

        unsigned key[8];
        #pragma unroll
        for (int k = 0; k < 8; ++k) {
            f32x4 v = __builtin_nontemporal_load(
                reinterpret_cast<const f32x4*>(p + k * 256));
            unsigned k0 = (__float_as_uint(v[0]) & 0xFFFFFF80u) | (base7 - 0);
            unsigned k1 = (__float_as_uint(v[1]) & 0xFFFFFF80u) | (base7 - 1);
            unsigned k2 = (__float_as_uint(v[2]) & 0xFFFFFF80u) | (base7 - 2);
            unsigned k3 = (__float_as_uint(v[3]) & 0xFFFFFF80u) | (base7 - 3);
            key[k] = umax2(umax2(k0, k1), umax2(k2, k3));
        }

        // 8 independent butterflies, interleaved (xor<32 stays in each half)
        #pragma unroll
        for (int off = 1; off < 32; off <<= 1) {
            #pragma unroll
            for (int k = 0; k < 8; ++k) {
                unsigned o = (unsigned)__shfl_xor((int)key[k], off);
                key[k] = umax2(key[k], o);
            }
        }

        if (s == 0) {
            #pragma unroll
            for (int k = 0; k < 8; ++k) {
                float conf = __uint_as_float(key[k] & 0xFFFFFF80u);
                int   idx  = 127 - (int)(key[k] & 127u);
                int b = (int)ceilf(conf * 15.0f) - 1;
                b = min(max(b, 0), ECE_N_BINS - 1);
                atomicAdd(&s_h[wv][0][b], conf);
                atomicAdd(&s_h[wv][1][b], (lab[k] == idx) ? 1.0f : 0.0f);
            }
        }
    }

    // fine-grained tail: rows [iters*nWaves*16, N), 2 rows per wave-iter
    const long long rowTail0 = (iters * nWaves) << 4;
    for (long long pr = rowTail0 + 2 * waveId; pr < N; pr += 2 * nWaves) {
        const long long row = pr + half;
        unsigned key = 0;
        if (row < N) {
            f32x4 v = __builtin_nontemporal_load(
                reinterpret_cast<const f32x4*>(sm + (row << 7) + (s << 2)));
            unsigned k0 = (__float_as_uint(v[0]) & 0xFFFFFF80u) | (base7 - 0);
            unsigned k1 = (__float_as_uint(v[1]) & 0xFFFFFF80u) | (base7 - 1);
            unsigned k2 = (__float_as_uint(v[2]) & 0xFFFFFF80u) | (base7 - 2);
            unsigned k3 = (__float_as_uint(v[3]) & 0xFFFFFF80u) | (base7 - 3);
            key = umax2(umax2(k0, k1), umax2(k2, k3));
        }
        #pragma unroll
        for (int off = 1; off < 32; off <<= 1)
            key = umax2(key, (unsigned)__shfl_xor((int)key, off));
        if (s == 0 && row < N) {
            float conf = __uint_as_float(key & 0xFFFFFF80u);
            int   idx  = 127 - (int)(key & 127u);
            int b = (int)ceilf(conf * 15.0f) - 1;
            b = min(max(b, 0), ECE_N_BINS - 1);
            atomicAdd(&s_h[wv][0][b], conf);
            atomicAdd(&s_h[wv][1][b], (labels[row] == idx) ? 1.0f : 0.0f);
        }
    }

    // block epilogue: fold per-wave histograms into global sums (device-scope
    // atomics are cross-XCD coherent), then last-block final reduction.
    __syncthreads();
    if (t < ECE_N_BINS) {
        float v = s_h[0][0][t] + s_h[1][0][t] + s_h[2][0][t] + s_h[3][0][t];
        atomicAdd(&ws[t], v);
    } else if (t >= 64 && t < 64 + ECE_N_BINS) {
        int b = t - 64;
        float v = s_h[0][1][b] + s_h[1][1][b] + s_h[2][1][b] + s_h[3][1][b];
        atomicAdd(&ws[ECE_N_BINS + b], v);
    }
    __syncthreads();
    __threadfence();                      // release our atomics before counting
    if (t == 0) {
        unsigned old = atomicAdd((unsigned*)&ws[2 * ECE_N_BINS], 1u);
        s_last = (old == (unsigned)gridDim.x - 1u) ? 1 : 0;
    }
    __syncthreads();
    if (s_last && t == 0) {
        __threadfence();                  // acquire side
        float e = 0.0f;
        #pragma unroll
        for (int b = 0; b < ECE_N_BINS; ++b) {
            // coherent reads via atomic RMW (+0) — immune to stale L1/L2
            float cs = atomicAdd(&ws[b], 0.0f);
            float as = atomicAdd(&ws[ECE_N_BINS + b], 0.0f);
            e += fabsf(cs - as);
        }
        out[0] = e / (float)N;
    }
}

extern "C" void kernel_launch(void* const* d_in, const int* in_sizes, int n_in,
                              void* d_out, int out_size, void* d_ws, size_t ws_size,
                              hipStream_t stream) {
    const float* sm     = (const float*)d_in[0];
    const int*   labels = (const int*)d_in[1];
    float*       out    = (float*)d_out;
    float*       ws     = (float*)d_ws;

    const int N = in_sizes[0] / 128;

    // zero sums + completion counter (graph-capture-legal async memset)
    hipMemsetAsync(ws, 0, 128, stream);

    const int block = 256;              // 4 waves/block
    const int grid  = 2048;             // 8 blocks/CU x 256 CUs, all resident
    ece_fused<<<grid, block, 0, stream>>>(sm, labels, ws, out, N);
}

// Round 6
// 180.003 us; speedup vs baseline: 2.9234x; 2.9234x over previous
//
#include <hip/hip_runtime.h>

#define ECE_N_BINS 15

typedef float f32x4 __attribute__((ext_vector_type(4)));

static __device__ __forceinline__ unsigned umax2(unsigned a, unsigned b) {
    return a > b ? a : b;
}

// Zero the 30-float accumulator in d_ws. Kernel node, NOT hipMemsetAsync:
// a memset node in the captured graph ran on the fill/blit path and cost
// ~350 us/replay of cross-queue serialization (R5 post-mortem).
__global__ void ece_zero_ws(float* __restrict__ ws) {
    int t = threadIdx.x;
    if (t < 2 * ECE_N_BINS) ws[t] = 0.0f;
}

// One 64-lane wave owns 16 consecutive rows (8 KB) per iteration: lanes 0-31
// handle even rows, 32-63 odd rows; each lane issues 8 independent
// nontemporal float4 loads. Max+argmax fused into one u32 key per row:
//   key = (float_bits & ~127) | (127 - col)
// (positive floats are bit-order-monotonic; low 7 bits break ties toward the
// first occurrence, matching jnp.argmax). Butterfly = 5 shfl + 5 umax.
// All waves run EXACTLY nChunks/nWaves iterations (no last-iteration skew);
// leftover rows go through a fine-grained 2-row/wave tail loop.
__global__ __launch_bounds__(256) void ece_main(const float* __restrict__ sm,
                                                const int* __restrict__ labels,
                                                float* __restrict__ ws,
                                                int N) {
    __shared__ float s_h[4][2][ECE_N_BINS];   // per-wave histograms

    const int t    = threadIdx.x;
    const int wv   = t >> 6;
    const int lane = t & 63;
    const int half = lane >> 5;          // row parity
    const int s    = lane & 31;          // column group: cols 4s..4s+3
    if (lane < 2 * ECE_N_BINS) ((float*)&s_h[wv][0][0])[lane] = 0.0f;
    __syncthreads();

    const long long waveId = (long long)blockIdx.x * 4 + wv;
    const long long nWaves = (long long)gridDim.x * 4;
    const long long nChunks = (long long)N >> 4;        // 16 rows per chunk
    const long long iters   = nChunks / nWaves;         // uniform per wave

    const float* p = sm + (waveId << 11) + (half << 7) + (s << 2);
    const long long pStride = nWaves << 11;             // floats per stride
    const unsigned base7 = (unsigned)(127 - 4 * s);     // 127 - col base

    for (long long i = 0; i < iters; ++i, p += pStride) {
        const long long c = waveId + i * nWaves;

        // early label prefetch: latency hides under key-build + butterfly
        int lab[8];
        if (s == 0) {
            const long long row0 = (c << 4) + half;
            #pragma unroll
            for (int k = 0; k < 8; ++k) lab[k] = labels[row0 + 2 * k];
        }

        unsigned key[8];
        #pragma unroll
        for (int k = 0; k < 8; ++k) {
            f32x4 v = __builtin_nontemporal_load(
                reinterpret_cast<const f32x4*>(p + k * 256));
            unsigned k0 = (__float_as_uint(v[0]) & 0xFFFFFF80u) | (base7 - 0);
            unsigned k1 = (__float_as_uint(v[1]) & 0xFFFFFF80u) | (base7 - 1);
            unsigned k2 = (__float_as_uint(v[2]) & 0xFFFFFF80u) | (base7 - 2);
            unsigned k3 = (__float_as_uint(v[3]) & 0xFFFFFF80u) | (base7 - 3);
            key[k] = umax2(umax2(k0, k1), umax2(k2, k3));
        }

        // 8 independent butterflies, interleaved (xor<32 stays in each half)
        #pragma unroll
        for (int off = 1; off < 32; off <<= 1) {
            #pragma unroll
            for (int k = 0; k < 8; ++k) {
                unsigned o = (unsigned)__shfl_xor((int)key[k], off);
                key[k] = umax2(key[k], o);
            }
        }

        if (s == 0) {
            #pragma unroll
            for (int k = 0; k < 8; ++k) {
                float conf = __uint_as_float(key[k] & 0xFFFFFF80u);
                int   idx  = 127 - (int)(key[k] & 127u);
                int b = (int)ceilf(conf * 15.0f) - 1;
                b = min(max(b, 0), ECE_N_BINS - 1);
                atomicAdd(&s_h[wv][0][b], conf);
                atomicAdd(&s_h[wv][1][b], (lab[k] == idx) ? 1.0f : 0.0f);
            }
        }
    }

    // fine-grained tail: rows [iters*nWaves*16, N), 2 rows per wave-iter
    const long long rowTail0 = (iters * nWaves) << 4;
    for (long long pr = rowTail0 + 2 * waveId; pr < N; pr += 2 * nWaves) {
        const long long row = pr + half;
        unsigned key = 0;
        if (row < N) {
            f32x4 v = __builtin_nontemporal_load(
                reinterpret_cast<const f32x4*>(sm + (row << 7) + (s << 2)));
            unsigned k0 = (__float_as_uint(v[0]) & 0xFFFFFF80u) | (base7 - 0);
            unsigned k1 = (__float_as_uint(v[1]) & 0xFFFFFF80u) | (base7 - 1);
            unsigned k2 = (__float_as_uint(v[2]) & 0xFFFFFF80u) | (base7 - 2);
            unsigned k3 = (__float_as_uint(v[3]) & 0xFFFFFF80u) | (base7 - 3);
            key = umax2(umax2(k0, k1), umax2(k2, k3));
        }
        #pragma unroll
        for (int off = 1; off < 32; off <<= 1)
            key = umax2(key, (unsigned)__shfl_xor((int)key, off));
        if (s == 0 && row < N) {
            float conf = __uint_as_float(key & 0xFFFFFF80u);
            int   idx  = 127 - (int)(key & 127u);
            int b = (int)ceilf(conf * 15.0f) - 1;
            b = min(max(b, 0), ECE_N_BINS - 1);
            atomicAdd(&s_h[wv][0][b], conf);
            atomicAdd(&s_h[wv][1][b], (labels[row] == idx) ? 1.0f : 0.0f);
        }
    }

    __syncthreads();
    if (t < ECE_N_BINS) {
        float v = s_h[0][0][t] + s_h[1][0][t] + s_h[2][0][t] + s_h[3][0][t];
        atomicAdd(&ws[t], v);
    } else if (t >= 64 && t < 64 + ECE_N_BINS) {
        int b = t - 64;
        float v = s_h[0][1][b] + s_h[1][1][b] + s_h[2][1][b] + s_h[3][1][b];
        atomicAdd(&ws[ECE_N_BINS + b], v);
    }
}

// Final: ece = sum_bins |sum_conf - sum_acc| / N
__global__ void ece_final(const float* __restrict__ ws,
                          float* __restrict__ out, int N) {
    if (threadIdx.x == 0 && blockIdx.x == 0) {
        float e = 0.0f;
        #pragma unroll
        for (int i = 0; i < ECE_N_BINS; ++i)
            e += fabsf(ws[i] - ws[ECE_N_BINS + i]);
        out[0] = e / (float)N;
    }
}

extern "C" void kernel_launch(void* const* d_in, const int* in_sizes, int n_in,
                              void* d_out, int out_size, void* d_ws, size_t ws_size,
                              hipStream_t stream) {
    const float* sm     = (const float*)d_in[0];
    const int*   labels = (const int*)d_in[1];
    float*       out    = (float*)d_out;
    float*       ws     = (float*)d_ws;

    const int N = in_sizes[0] / 128;

    ece_zero_ws<<<1, 64, 0, stream>>>(ws);

    const int block = 256;              // 4 waves/block
    const int grid  = 2048;             // 8 blocks/CU x 256 CUs, all resident
    ece_main<<<grid, block, 0, stream>>>(sm, labels, ws, N);

    ece_final<<<1, 64, 0, stream>>>(ws, out, N);
}